// Round 1
// baseline (855.180 us; speedup 1.0000x reference)
//
#include <hip/hip_runtime.h>

// GCNConv scatter: out[src[e]] += feat[dst[e]] * w[e]
// feat: [100000, 64] f32, w: [1000000] f32, src/dst: [1000000] int (int64 in
// ref, harness passes int32), out: [100000, 64] f32.

#define N_NODES 100000
#define N_EDGES 1000000
#define D_FEAT  64

// 16 threads per edge; each thread handles 4 consecutive floats (float4).
__global__ __launch_bounds__(256) void gcn_scatter_kernel(
    const float* __restrict__ feat,
    const float* __restrict__ w,
    const int*   __restrict__ src,
    const int*   __restrict__ dst,
    float* __restrict__ out,
    int n_edges)
{
    int tid  = blockIdx.x * blockDim.x + threadIdx.x;
    int edge = tid >> 4;        // 16 threads per edge
    int lane = tid & 15;        // 0..15, each covers 4 floats

    if (edge >= n_edges) return;

    int s = src[edge];
    int d = dst[edge];
    float ww = w[edge];

    const float4 v = *reinterpret_cast<const float4*>(&feat[(size_t)d * D_FEAT + lane * 4]);
    float* o = &out[(size_t)s * D_FEAT + lane * 4];

    atomicAdd(o + 0, v.x * ww);
    atomicAdd(o + 1, v.y * ww);
    atomicAdd(o + 2, v.z * ww);
    atomicAdd(o + 3, v.w * ww);
}

extern "C" void kernel_launch(void* const* d_in, const int* in_sizes, int n_in,
                              void* d_out, int out_size, void* d_ws, size_t ws_size,
                              hipStream_t stream) {
    const float* feat = (const float*)d_in[0];
    const float* w    = (const float*)d_in[1];
    const int*   src  = (const int*)d_in[2];
    const int*   dst  = (const int*)d_in[3];
    float* out = (float*)d_out;

    int n_edges = in_sizes[1];  // edge_weight count = E

    // Harness poisons d_out with 0xAA and does not re-poison between replays:
    // zero it every call.
    hipMemsetAsync(d_out, 0, (size_t)out_size * sizeof(float), stream);

    // 16 threads/edge -> 16*E total threads.
    int threads = 256;
    long long total = (long long)n_edges * 16;
    int blocks = (int)((total + threads - 1) / threads);
    gcn_scatter_kernel<<<blocks, threads, 0, stream>>>(feat, w, src, dst, out, n_edges);
}

// Round 2
// 183.340 us; speedup vs baseline: 4.6644x; 4.6644x over previous
//
#include <hip/hip_runtime.h>

// GCNConv: out[src[e]] += feat[dst[e]] * w[e]
// Strategy: build CSR grouped by src on-device (hist -> scan -> scatter),
// then segment-sum with plain stores (no float atomics).
//
// feat: [N,64] f32, w: [E] f32, src/dst: [E] int32 (harness converts int64).

#define D_FEAT     64
#define SCAN_CHUNK 2048

// ---------------- fallback (round-1 atomic path) ----------------
__global__ __launch_bounds__(256) void gcn_scatter_atomic(
    const float* __restrict__ feat, const float* __restrict__ w,
    const int* __restrict__ src, const int* __restrict__ dst,
    float* __restrict__ out, int n_edges)
{
    int tid  = blockIdx.x * blockDim.x + threadIdx.x;
    int edge = tid >> 4;
    int lane = tid & 15;
    if (edge >= n_edges) return;
    int s = src[edge], d = dst[edge];
    float ww = w[edge];
    const float4 v = *reinterpret_cast<const float4*>(&feat[(size_t)d * D_FEAT + lane * 4]);
    float* o = &out[(size_t)s * D_FEAT + lane * 4];
    atomicAdd(o + 0, v.x * ww);
    atomicAdd(o + 1, v.y * ww);
    atomicAdd(o + 2, v.z * ww);
    atomicAdd(o + 3, v.w * ww);
}

// ---------------- CSR build ----------------
__global__ __launch_bounds__(256) void hist_kernel(
    const int* __restrict__ src, int* __restrict__ counts, int E)
{
    int e = blockIdx.x * blockDim.x + threadIdx.x;
    if (e < E) atomicAdd(&counts[src[e]], 1);
}

// Per-chunk exclusive scan: 256 threads x 8 elems = 2048/block.
__global__ __launch_bounds__(256) void scan_blocks(
    const int* __restrict__ counts, int* __restrict__ offsets,
    int* __restrict__ block_sums, int N)
{
    __shared__ int sh[256];
    int base = blockIdx.x * SCAN_CHUNK;
    int t = threadIdx.x;
    int v[8];
    int s = 0;
    #pragma unroll
    for (int k = 0; k < 8; k++) {
        int g = base + t * 8 + k;
        v[k] = (g < N) ? counts[g] : 0;
        s += v[k];
    }
    sh[t] = s;
    __syncthreads();
    // Hillis-Steele inclusive scan over 256 thread sums.
    for (int off = 1; off < 256; off <<= 1) {
        int x = (t >= off) ? sh[t - off] : 0;
        __syncthreads();
        sh[t] += x;
        __syncthreads();
    }
    int run = (t == 0) ? 0 : sh[t - 1];   // exclusive prefix for this thread
    if (t == 255) block_sums[blockIdx.x] = sh[255];
    #pragma unroll
    for (int k = 0; k < 8; k++) {
        int g = base + t * 8 + k;
        if (g < N) offsets[g] = run;
        run += v[k];
    }
}

// Serial scan over block sums (nblk ~= 49, trivial). Also writes offsets[N].
__global__ void scan_sums(int* __restrict__ block_sums, int* __restrict__ offsets,
                          int nblk, int N)
{
    if (blockIdx.x == 0 && threadIdx.x == 0) {
        int run = 0;
        for (int b = 0; b < nblk; b++) {
            int c = block_sums[b];
            block_sums[b] = run;
            run += c;
        }
        offsets[N] = run;  // == E
    }
}

__global__ __launch_bounds__(256) void scan_add(
    int* __restrict__ offsets, const int* __restrict__ block_sums, int N)
{
    int g = blockIdx.x * blockDim.x + threadIdx.x;
    if (g < N) offsets[g] += block_sums[g / SCAN_CHUNK];
}

// Scatter edges into src-grouped order. counts[] (== degree after hist) is
// consumed as a cursor via atomicSub; ends at 0.
__global__ __launch_bounds__(256) void scatter_kernel(
    const int* __restrict__ src, const int* __restrict__ dst,
    const float* __restrict__ w, const int* __restrict__ offsets,
    int* __restrict__ cursor, int* __restrict__ dst_sorted,
    float* __restrict__ w_sorted, int E)
{
    int e = blockIdx.x * blockDim.x + threadIdx.x;
    if (e >= E) return;
    int s = src[e];
    int old = atomicSub(&cursor[s], 1);       // old in [1..deg]
    int pos = offsets[s] + old - 1;
    dst_sorted[pos] = dst[e];
    w_sorted[pos]   = w[e];
}

// ---------------- segment sum (no atomics) ----------------
// 16 threads per node; each owns 4 consecutive floats (float4 column slice).
__global__ __launch_bounds__(256) void segment_kernel(
    const float* __restrict__ feat, const int* __restrict__ offsets,
    const int* __restrict__ dst_sorted, const float* __restrict__ w_sorted,
    float* __restrict__ out, int N)
{
    int tid  = blockIdx.x * blockDim.x + threadIdx.x;
    int node = tid >> 4;
    int q    = tid & 15;
    if (node >= N) return;
    int start = offsets[node];
    int end   = offsets[node + 1];
    float4 acc = {0.f, 0.f, 0.f, 0.f};
    for (int j = start; j < end; j++) {
        int   d  = dst_sorted[j];
        float ww = w_sorted[j];
        float4 v = *reinterpret_cast<const float4*>(&feat[(size_t)d * D_FEAT + q * 4]);
        acc.x += v.x * ww;
        acc.y += v.y * ww;
        acc.z += v.z * ww;
        acc.w += v.w * ww;
    }
    *reinterpret_cast<float4*>(&out[(size_t)node * D_FEAT + q * 4]) = acc;
}

extern "C" void kernel_launch(void* const* d_in, const int* in_sizes, int n_in,
                              void* d_out, int out_size, void* d_ws, size_t ws_size,
                              hipStream_t stream) {
    const float* feat = (const float*)d_in[0];
    const float* w    = (const float*)d_in[1];
    const int*   src  = (const int*)d_in[2];
    const int*   dst  = (const int*)d_in[3];
    float* out = (float*)d_out;

    int N = out_size / D_FEAT;   // 100000
    int E = in_sizes[1];         // 1000000
    int nblk = (N + SCAN_CHUNK - 1) / SCAN_CHUNK;

    // ws layout: counts[N] | offsets[N+1] | block_sums[pad] | dst_sorted[E] | w_sorted[E]
    int* counts     = (int*)d_ws;
    int* offsets    = counts + N;
    int* block_sums = offsets + (N + 1);
    int* dst_sorted = block_sums + ((nblk + 3) & ~3);
    float* w_sorted = (float*)(dst_sorted + E);
    size_t need = (size_t)((char*)(w_sorted + E) - (char*)d_ws);

    if (ws_size < need) {
        // Not enough scratch: atomic fallback.
        hipMemsetAsync(d_out, 0, (size_t)out_size * sizeof(float), stream);
        long long total = (long long)E * 16;
        int blocks = (int)((total + 255) / 256);
        gcn_scatter_atomic<<<blocks, 256, 0, stream>>>(feat, w, src, dst, out, E);
        return;
    }

    hipMemsetAsync(counts, 0, (size_t)N * sizeof(int), stream);

    hist_kernel<<<(E + 255) / 256, 256, 0, stream>>>(src, counts, E);
    scan_blocks<<<nblk, 256, 0, stream>>>(counts, offsets, block_sums, N);
    scan_sums<<<1, 64, 0, stream>>>(block_sums, offsets, nblk, N);
    scan_add<<<(N + 255) / 256, 256, 0, stream>>>(offsets, block_sums, N);
    scatter_kernel<<<(E + 255) / 256, 256, 0, stream>>>(src, dst, w, offsets,
                                                        counts, dst_sorted, w_sorted, E);

    long long segthreads = (long long)N * 16;
    segment_kernel<<<(int)((segthreads + 255) / 256), 256, 0, stream>>>(
        feat, offsets, dst_sorted, w_sorted, out, N);
}

// Round 3
// 168.967 us; speedup vs baseline: 5.0612x; 1.0851x over previous
//
#include <hip/hip_runtime.h>

// GCNConv: out[src[e]] += feat[dst[e]] * w[e]
// CSR build (hist -> scan -> scatter) + segment-sum with plain stores.
// Round-3 change: pack (dst, w) into a single int2 so the random scatter
// does ONE 8B store per edge (halves dirtied cache lines).
//
// feat: [N,64] f32, w: [E] f32, src/dst: [E] int32 (harness converts int64).

#define D_FEAT     64
#define SCAN_CHUNK 2048

// ---------------- CSR build ----------------
__global__ __launch_bounds__(256) void hist_kernel(
    const int* __restrict__ src, int* __restrict__ counts, int E)
{
    int e = blockIdx.x * blockDim.x + threadIdx.x;
    if (e < E) atomicAdd(&counts[src[e]], 1);
}

// Per-chunk exclusive scan: 256 threads x 8 elems = 2048/block.
__global__ __launch_bounds__(256) void scan_blocks(
    const int* __restrict__ counts, int* __restrict__ offsets,
    int* __restrict__ block_sums, int N)
{
    __shared__ int sh[256];
    int base = blockIdx.x * SCAN_CHUNK;
    int t = threadIdx.x;
    int v[8];
    int s = 0;
    #pragma unroll
    for (int k = 0; k < 8; k++) {
        int g = base + t * 8 + k;
        v[k] = (g < N) ? counts[g] : 0;
        s += v[k];
    }
    sh[t] = s;
    __syncthreads();
    for (int off = 1; off < 256; off <<= 1) {
        int x = (t >= off) ? sh[t - off] : 0;
        __syncthreads();
        sh[t] += x;
        __syncthreads();
    }
    int run = (t == 0) ? 0 : sh[t - 1];
    if (t == 255) block_sums[blockIdx.x] = sh[255];
    #pragma unroll
    for (int k = 0; k < 8; k++) {
        int g = base + t * 8 + k;
        if (g < N) offsets[g] = run;
        run += v[k];
    }
}

__global__ void scan_sums(int* __restrict__ block_sums, int* __restrict__ offsets,
                          int nblk, int N)
{
    if (blockIdx.x == 0 && threadIdx.x == 0) {
        int run = 0;
        for (int b = 0; b < nblk; b++) {
            int c = block_sums[b];
            block_sums[b] = run;
            run += c;
        }
        offsets[N] = run;  // == E
    }
}

__global__ __launch_bounds__(256) void scan_add(
    int* __restrict__ offsets, const int* __restrict__ block_sums, int N)
{
    int g = blockIdx.x * blockDim.x + threadIdx.x;
    if (g < N) offsets[g] += block_sums[g / SCAN_CHUNK];
}

// Scatter edges into src-grouped order, ONE int2 (dst, w-bits) store per edge.
__global__ __launch_bounds__(256) void scatter_kernel(
    const int* __restrict__ src, const int* __restrict__ dst,
    const float* __restrict__ w, const int* __restrict__ offsets,
    int* __restrict__ cursor, int2* __restrict__ edge_packed, int E)
{
    int e = blockIdx.x * blockDim.x + threadIdx.x;
    if (e >= E) return;
    int s = src[e];
    int d = dst[e];
    float ww = w[e];
    int old = atomicSub(&cursor[s], 1);       // old in [1..deg]
    int pos = offsets[s] + old - 1;
    edge_packed[pos] = make_int2(d, __float_as_int(ww));
}

// ---------------- segment sum (no atomics) ----------------
// 16 threads per node; each owns 4 consecutive floats (float4 column slice).
__global__ __launch_bounds__(256) void segment_kernel(
    const float* __restrict__ feat, const int* __restrict__ offsets,
    const int2* __restrict__ edge_packed, float* __restrict__ out, int N)
{
    int tid  = blockIdx.x * blockDim.x + threadIdx.x;
    int node = tid >> 4;
    int q    = tid & 15;
    if (node >= N) return;
    int start = offsets[node];
    int end   = offsets[node + 1];
    float4 acc = {0.f, 0.f, 0.f, 0.f};
    int j = start;
    // 2-wide unroll for memory-level parallelism.
    for (; j + 2 <= end; j += 2) {
        int2 ep0 = edge_packed[j];
        int2 ep1 = edge_packed[j + 1];
        float w0 = __int_as_float(ep0.y);
        float w1 = __int_as_float(ep1.y);
        float4 v0 = *reinterpret_cast<const float4*>(&feat[(size_t)ep0.x * D_FEAT + q * 4]);
        float4 v1 = *reinterpret_cast<const float4*>(&feat[(size_t)ep1.x * D_FEAT + q * 4]);
        acc.x += v0.x * w0; acc.y += v0.y * w0; acc.z += v0.z * w0; acc.w += v0.w * w0;
        acc.x += v1.x * w1; acc.y += v1.y * w1; acc.z += v1.z * w1; acc.w += v1.w * w1;
    }
    if (j < end) {
        int2 ep = edge_packed[j];
        float ww = __int_as_float(ep.y);
        float4 v = *reinterpret_cast<const float4*>(&feat[(size_t)ep.x * D_FEAT + q * 4]);
        acc.x += v.x * ww; acc.y += v.y * ww; acc.z += v.z * ww; acc.w += v.w * ww;
    }
    *reinterpret_cast<float4*>(&out[(size_t)node * D_FEAT + q * 4]) = acc;
}

extern "C" void kernel_launch(void* const* d_in, const int* in_sizes, int n_in,
                              void* d_out, int out_size, void* d_ws, size_t ws_size,
                              hipStream_t stream) {
    const float* feat = (const float*)d_in[0];
    const float* w    = (const float*)d_in[1];
    const int*   src  = (const int*)d_in[2];
    const int*   dst  = (const int*)d_in[3];
    float* out = (float*)d_out;

    int N = out_size / D_FEAT;   // 100000
    int E = in_sizes[1];         // 1000000
    int nblk = (N + SCAN_CHUNK - 1) / SCAN_CHUNK;

    // ws layout: counts[N] | offsets[N+1] | block_sums[pad] | edge_packed[E] (8B aligned)
    int* counts     = (int*)d_ws;
    int* offsets    = counts + N;
    int* block_sums = offsets + (N + 1);
    int* after_bs   = block_sums + ((nblk + 3) & ~3);
    // align to 8B for int2
    uintptr_t ap = ((uintptr_t)after_bs + 7) & ~(uintptr_t)7;
    int2* edge_packed = (int2*)ap;
    size_t need = (size_t)((char*)(edge_packed + E) - (char*)d_ws);
    (void)need; (void)ws_size;   // passed round 2 with larger footprint

    hipMemsetAsync(counts, 0, (size_t)N * sizeof(int), stream);

    hist_kernel<<<(E + 255) / 256, 256, 0, stream>>>(src, counts, E);
    scan_blocks<<<nblk, 256, 0, stream>>>(counts, offsets, block_sums, N);
    scan_sums<<<1, 64, 0, stream>>>(block_sums, offsets, nblk, N);
    scan_add<<<(N + 255) / 256, 256, 0, stream>>>(offsets, block_sums, N);
    scatter_kernel<<<(E + 255) / 256, 256, 0, stream>>>(src, dst, w, offsets,
                                                        counts, edge_packed, E);

    long long segthreads = (long long)N * 16;
    segment_kernel<<<(int)((segthreads + 255) / 256), 256, 0, stream>>>(
        feat, offsets, edge_packed, out, N);
}